// Round 2
// baseline (355.777 us; speedup 1.0000x reference)
//
#include <hip/hip_runtime.h>
#include <hip/hip_bf16.h>

using bf16 = __hip_bfloat16;
typedef __bf16 bf16x8 __attribute__((ext_vector_type(8)));
typedef float f32x4 __attribute__((ext_vector_type(4)));

#define MT 32          // tokens per block
#define SX 136         // xs row stride (elems): 128 + 8 pad
#define SH 264         // hs row stride: 256 + 8
#define SR 552         // node row stride: 544 + 8 pad (1104 B = 276 banks == 20 mod 32
                       //  -> 16-row ds_read_b128 fragments hit 8 bank slots = 2-way = free)
// LDS (bf16 elems), 17664 total = 35328 B:
//   xs: [32][136] @ 0      (dead after GEMM1)
//   hs: [32][264] @ 4352   (dead after GEMM2's register capture)
//   nb: [32][552] @ 0      (node buffer, overlays xs+hs; GEMM2 out, GATs in-place, coord in)

__device__ __forceinline__ float bf2f(bf16 v) { return __bfloat162float(v); }

__device__ __forceinline__ float gelu_f(float x) {
    // tanh-approx GELU; |err vs erf-gelu| <= ~3e-3 abs, fine vs 2%-of-max threshold
    float u  = 0.7978845608f * x * (1.0f + 0.044715f * x * x);
    float au = fabsf(u);
    float e  = __expf(-2.0f * au);
    float t  = (1.0f - e) / (1.0f + e);
    t = (u < 0.0f) ? -t : t;
    return 0.5f * x * (1.0f + t);
}

__device__ __forceinline__ bf16x8 ld8(const bf16* p) {
    return *reinterpret_cast<const bf16x8*>(p);
}
__device__ __forceinline__ f32x4 mfma16(bf16x8 a, bf16x8 b, f32x4 c) {
    return __builtin_amdgcn_mfma_f32_16x16x32_bf16(a, b, c, 0, 0, 0);
}

// ---------------- prep 1: weight transposes + adjacency softmax ----------------
__global__ void prep_kernel(const float* __restrict__ W1, const float* __restrict__ W2,
                            const float* __restrict__ adj1, const float* __restrict__ adj2,
                            bf16* __restrict__ w1t, bf16* __restrict__ w2t,
                            float* __restrict__ A1f, float* __restrict__ A2f) {
    int idx = blockIdx.x * 256 + threadIdx.x;
    if (idx < 32768) {                       // W1: r=k(128), c=n(256)
        int r = idx >> 8, c = idx & 255;
        w1t[c * 128 + r] = __float2bfloat16(W1[idx]);
    } else if (idx < 172032) {               // W2: r=k(256), c=n(544)
        int j = idx - 32768;
        int r = j / 544, c = j % 544;
        w2t[c * 256 + r] = __float2bfloat16(W2[j]);
    }
    if (blockIdx.x == 0) {
        int t = threadIdx.x;
        if (t < 17 || (t >= 32 && t < 49)) {
            const float* adj = (t < 17) ? adj1 : adj2;
            float*       A   = (t < 17) ? A1f  : A2f;
            int row = (t < 17) ? t : (t - 32);
            float v[17]; float mx = -1e30f;
            for (int j = 0; j < 17; ++j) { v[j] = adj[row * 17 + j]; mx = fmaxf(mx, v[j]); }
            float s = 0.0f;
            for (int j = 0; j < 17; ++j) { v[j] = __expf(v[j] - mx); s += v[j]; }
            float inv = 1.0f / s;
            for (int j = 0; j < 17; ++j) A[row * 17 + j] = v[j] * inv;
        }
    }
}

// ---------------- prep 2: Kronecker GAT matrices K = A (x) Wg ----------------
// K[n=(i*32+f')][k=(j*32+f)] = A[i][j] * Wg[f][f'], stored B-fragment-tiled:
// elem -> [((n>>4)*17 + (k>>5))*512 + (n&15)*32 + (k&31)] so each wave ld8 of a
// fragment is one contiguous 1 KB line.
__global__ void prep2_kernel(const float* __restrict__ Wg1, const float* __restrict__ Wg2,
                             const float* __restrict__ A1f, const float* __restrict__ A2f,
                             bf16* __restrict__ k1, bf16* __restrict__ k2) {
    int idx = blockIdx.x * 256 + threadIdx.x;      // covers 2*544*544 exactly
    int g = idx / (544 * 544);
    int r = idx - g * (544 * 544);
    int n = r / 544;
    int k = r - n * 544;
    int i = n >> 5, fp = n & 31;
    int j = k >> 5, f  = k & 31;
    const float* A  = g ? A2f : A1f;
    const float* Wg = g ? Wg2 : Wg1;
    bf16*        K  = g ? k2  : k1;
    float v = A[i * 17 + j] * Wg[f * 32 + fp];
    K[(((n >> 4) * 17 + (k >> 5)) << 9) + ((n & 15) << 5) + (k & 31)] = __float2bfloat16(v);
}

// ---------------- fused GAT layer, IN-PLACE: nb = gelu(nb @ K^T + bg) + nb ----------------
// Safe in-place: every thread pre-captures its full A-fragment set in registers,
// then a barrier, then compute. Each output cell (row,n) is read-modify-written
// by exactly one owning thread, so the residual read sees the original value.
__device__ __forceinline__ void gat_kron(bf16* __restrict__ nb,
                                         const bf16* __restrict__ km, const float* __restrict__ bg,
                                         int w, int l, int q) {
    bf16x8 afr[2][17];
#pragma unroll
    for (int mt = 0; mt < 2; ++mt)
#pragma unroll
        for (int ks = 0; ks < 17; ++ks)
            afr[mt][ks] = ld8(nb + (mt * 16 + l) * SR + ks * 32 + q * 8);
    __syncthreads();   // all captures done before any in-place write

    for (int nt = w; nt < 34; nt += 4) {
        int n = nt * 16 + l;
        float bias = bg[n & 31];
        f32x4 a0 = {0.f, 0.f, 0.f, 0.f}, a1 = {0.f, 0.f, 0.f, 0.f};
        const bf16* kp = km + nt * 17 * 512 + l * 32 + q * 8;
#pragma unroll
        for (int ks = 0; ks < 17; ++ks) {
            bf16x8 bfr = ld8(kp + ks * 512);
            a0 = mfma16(afr[0][ks], bfr, a0);
            a1 = mfma16(afr[1][ks], bfr, a1);
        }
#pragma unroll
        for (int mt = 0; mt < 2; ++mt) {
            const f32x4 acc = mt ? a1 : a0;
#pragma unroll
            for (int r = 0; r < 4; ++r) {
                int row = mt * 16 + q * 4 + r;
                int off = row * SR + n;
                float v = gelu_f(acc[r] + bias) + bf2f(nb[off]);
                nb[off] = __float2bfloat16(v);
            }
        }
    }
    __syncthreads();   // writes done before next consumer reads
}

// ---------------- main fused kernel ----------------
__global__ __launch_bounds__(256, 2)
void gat_main(const float* __restrict__ x,
              const float* __restrict__ b1, const float* __restrict__ b2,
              const float* __restrict__ bg1, const float* __restrict__ bg2,
              const bf16* __restrict__ w1t, const bf16* __restrict__ w2t,
              const bf16* __restrict__ k1, const bf16* __restrict__ k2,
              const float* __restrict__ Wc, const float* __restrict__ bc,
              float* __restrict__ out) {
    __shared__ alignas(16) bf16 S[17664];   // 35328 B
    bf16* xs = S;            // [32][SX]
    bf16* hs = S + 4352;     // [32][SH]
    bf16* nb = S;            // [32][SR] node buffer (overlays xs+hs)

    const int tid  = threadIdx.x;
    const int w    = tid >> 6;
    const int lane = tid & 63;
    const int l    = lane & 15;
    const int q    = lane >> 4;
    const int t0   = blockIdx.x * MT;

    // ---- stage x tile (fp32 -> bf16) ----
    for (int c = tid; c < 1024; c += 256) {
        int row = c >> 5, c4 = c & 31;
        const float4 v = *reinterpret_cast<const float4*>(x + (size_t)(t0 + row) * 128 + c4 * 4);
        bf16 tmp[4] = { __float2bfloat16(v.x), __float2bfloat16(v.y),
                        __float2bfloat16(v.z), __float2bfloat16(v.w) };
        *reinterpret_cast<ushort4*>(xs + row * SX + c4 * 4) =
            *reinterpret_cast<const ushort4*>(tmp);
    }
    __syncthreads();

    // ---- GEMM1: h = gelu(x @ W1 + b1)  [32,128]@[128,256] ----
    for (int nt = w * 4; nt < w * 4 + 4; ++nt) {
        int n = nt * 16 + l;
        bf16x8 bfr[4];
        const bf16* wp = w1t + n * 128 + q * 8;
#pragma unroll
        for (int kf = 0; kf < 4; ++kf) bfr[kf] = ld8(wp + kf * 32);
        float bias = b1[n];
#pragma unroll
        for (int mt = 0; mt < 2; ++mt) {
            f32x4 acc = {0.f, 0.f, 0.f, 0.f};
            const bf16* ap = xs + (mt * 16 + l) * SX + q * 8;
#pragma unroll
            for (int kf = 0; kf < 4; ++kf)
                acc = mfma16(ld8(ap + kf * 32), bfr[kf], acc);
            int trow = mt * 16 + q * 4;
#pragma unroll
            for (int r = 0; r < 4; ++r)
                hs[(trow + r) * SH + n] = __float2bfloat16(gelu_f(acc[r] + bias));
        }
    }
    __syncthreads();

    // ---- GEMM2: nodes = h @ W2 + b2  [32,256]@[256,544] -> nb (overlays hs) ----
    {
        bf16x8 af[2][8];    // register-capture all of this thread's hs fragments
#pragma unroll
        for (int mt = 0; mt < 2; ++mt)
#pragma unroll
            for (int kf = 0; kf < 8; ++kf)
                af[mt][kf] = ld8(hs + (mt * 16 + l) * SH + kf * 32 + q * 8);
        __syncthreads();     // hs fully captured before nb (overlaying hs) is written

        for (int nt = w; nt < 34; nt += 4) {
            int n = nt * 16 + l;
            float bias = b2[n];
            f32x4 a0 = {0.f, 0.f, 0.f, 0.f}, a1 = {0.f, 0.f, 0.f, 0.f};
            const bf16* wp = w2t + n * 256 + q * 8;
#pragma unroll
            for (int kf = 0; kf < 8; ++kf) {
                bf16x8 bfr = ld8(wp + kf * 32);
                a0 = mfma16(af[0][kf], bfr, a0);
                a1 = mfma16(af[1][kf], bfr, a1);
            }
#pragma unroll
            for (int mt = 0; mt < 2; ++mt) {
                const f32x4 acc = mt ? a1 : a0;
#pragma unroll
                for (int r = 0; r < 4; ++r) {
                    int row = mt * 16 + q * 4 + r;
                    nb[row * SR + n] = __float2bfloat16(acc[r] + bias);
                }
            }
        }
    }
    __syncthreads();

    // ---- GAT1 / GAT2 as dense Kronecker GEMMs, in place ----
    gat_kron(nb, k1, bg1, w, l, q);
    gat_kron(nb, k2, bg2, w, l, q);

    // ---- coord projection: out = g2 @ Wc + bc (fp32 output) ----
    for (int r = tid; r < 544; r += 256) {
        int t = r / 17, i = r % 17;
        float o0 = bc[0], o1 = bc[1];
        const __hip_bfloat162* gp =
            reinterpret_cast<const __hip_bfloat162*>(nb + t * SR + i * 32);
#pragma unroll
        for (int k2i = 0; k2i < 16; ++k2i) {
            __hip_bfloat162 p = gp[k2i];
            float a = bf2f(p.x), b = bf2f(p.y);
            int k = k2i * 2;
            o0 = fmaf(a, Wc[k * 2 + 0], o0);
            o1 = fmaf(a, Wc[k * 2 + 1], o1);
            o0 = fmaf(b, Wc[k * 2 + 2], o0);
            o1 = fmaf(b, Wc[k * 2 + 3], o1);
        }
        float2 pr = { o0, o1 };
        reinterpret_cast<float2*>(out)[(size_t)(t0 + t) * 17 + i] = pr;
    }
}

extern "C" void kernel_launch(void* const* d_in, const int* in_sizes, int n_in,
                              void* d_out, int out_size, void* d_ws, size_t ws_size,
                              hipStream_t stream) {
    const float* x    = (const float*)d_in[0];
    const float* W1   = (const float*)d_in[1];
    const float* b1   = (const float*)d_in[2];
    const float* W2   = (const float*)d_in[3];
    const float* b2   = (const float*)d_in[4];
    const float* adj1 = (const float*)d_in[5];
    const float* Wg1  = (const float*)d_in[6];
    const float* bg1  = (const float*)d_in[7];
    const float* adj2 = (const float*)d_in[8];
    const float* Wg2  = (const float*)d_in[9];
    const float* bg2  = (const float*)d_in[10];
    const float* Wc   = (const float*)d_in[11];
    const float* bc   = (const float*)d_in[12];

    char* ws = (char*)d_ws;
    bf16*  w1t = (bf16*)(ws + 0);          // 65536 B
    bf16*  w2t = (bf16*)(ws + 65536);      // 278528 B -> 344064
    bf16*  k1  = (bf16*)(ws + 344064);     // 591872 B -> 935936
    bf16*  k2  = (bf16*)(ws + 935936);     // 591872 B -> 1527808
    float* A1f = (float*)(ws + 1527808);   // 1156 B
    float* A2f = (float*)(ws + 1529856);   // 1156 B

    prep_kernel<<<672, 256, 0, stream>>>(W1, W2, adj1, adj2, w1t, w2t, A1f, A2f);
    prep2_kernel<<<2312, 256, 0, stream>>>(Wg1, Wg2, A1f, A2f, k1, k2);

    const int tokens = 16 * 4096;
    gat_main<<<tokens / MT, 256, 0, stream>>>(x, b1, b2, bg1, bg2,
                                              w1t, w2t, k1, k2,
                                              Wc, bc, (float*)d_out);
}

// Round 3
// 273.841 us; speedup vs baseline: 1.2992x; 1.2992x over previous
//
#include <hip/hip_runtime.h>
#include <hip/hip_bf16.h>

using bf16 = __hip_bfloat16;
typedef __bf16 bf16x4v __attribute__((ext_vector_type(4)));
typedef __bf16 bf16x8 __attribute__((ext_vector_type(8)));
typedef float f32x4 __attribute__((ext_vector_type(4)));

#define MT 32            // tokens per block
#define SX 136           // xs row stride: 128 + 8 pad
#define SH 264           // hs row stride: 256 + 8
#define SJ 20            // NTF j-stride: 17 joints + 3 zero pad (40 B rows, b64-aligned)
#define TFS 640          // NTF token stride = 32 * SJ
#define NTF_ELEMS 20480  // 32 tokens * 32 feats * SJ
#define NTF_TOTAL 20496  // + 16-elem zeroed tail (over-read window of last row)
#define MS_BASE 20496    // byte 40992, 16B-aligned
#define SMS 40           // Ms row stride (80 B: b128-aligned, 2-way banks max)
#define S_ELEMS 31376    // 20496 + 272*40  = 62752 B
// LDS plan:
//   xs [32][136] @ 0, hs [32][264] @ 4352   (GEMM1 phase; dead after hs reg-capture)
//   NTF[t][f][j] @ 0 elem (t*640 + f*20 + j)  node state, overlays xs+hs
//   Ms [272][40] @ 20496                       per-half mix output (t_loc*17+i rows)

__device__ __forceinline__ float bf2f(bf16 v) { return __bfloat162float(v); }

__device__ __forceinline__ float gelu_f(float x) {
    // tanh-approx GELU; |err vs erf-gelu| <= ~3e-3 abs, fine vs 2%-of-max threshold
    float u  = 0.7978845608f * x * (1.0f + 0.044715f * x * x);
    float au = fabsf(u);
    float e  = __expf(-2.0f * au);
    float t  = (1.0f - e) / (1.0f + e);
    t = (u < 0.0f) ? -t : t;
    return 0.5f * x * (1.0f + t);
}

__device__ __forceinline__ bf16x8 ld8(const bf16* p) {       // 16B-aligned
    return *reinterpret_cast<const bf16x8*>(p);
}
__device__ __forceinline__ bf16x8 ld8u(const bf16* p) {      // 8B-aligned (two b64)
    bf16x4v lo = *reinterpret_cast<const bf16x4v*>(p);
    bf16x4v hi = *reinterpret_cast<const bf16x4v*>(p + 4);
    return __builtin_shufflevector(lo, hi, 0, 1, 2, 3, 4, 5, 6, 7);
}
__device__ __forceinline__ f32x4 mfma16(bf16x8 a, bf16x8 b, f32x4 c) {
    return __builtin_amdgcn_mfma_f32_16x16x32_bf16(a, b, c, 0, 0, 0);
}

// ---------------- prep: weight transposes + adjacency softmax (round-0 proven) ----------------
__global__ void prep_kernel(const float* __restrict__ W1, const float* __restrict__ W2,
                            const float* __restrict__ Wg1, const float* __restrict__ Wg2,
                            const float* __restrict__ adj1, const float* __restrict__ adj2,
                            bf16* __restrict__ w1t, bf16* __restrict__ w2t,
                            bf16* __restrict__ wg1t, bf16* __restrict__ wg2t,
                            float* __restrict__ A1f, float* __restrict__ A2f) {
    int idx = blockIdx.x * 256 + threadIdx.x;
    if (idx < 32768) {                       // W1: r=k(128), c=n(256)
        int r = idx >> 8, c = idx & 255;
        w1t[c * 128 + r] = __float2bfloat16(W1[idx]);
    } else if (idx < 172032) {               // W2: r=k(256), c=n(544)
        int j = idx - 32768;
        int r = j / 544, c = j % 544;
        w2t[c * 256 + r] = __float2bfloat16(W2[j]);
    } else if (idx < 173056) {               // Wg1 -> wg1t[f'][f]
        int j = idx - 172032;
        wg1t[(j & 31) * 32 + (j >> 5)] = __float2bfloat16(Wg1[j]);
    } else if (idx < 174080) {
        int j = idx - 173056;
        wg2t[(j & 31) * 32 + (j >> 5)] = __float2bfloat16(Wg2[j]);
    }
    if (blockIdx.x == 0) {
        int t = threadIdx.x;
        if (t < 17 || (t >= 32 && t < 49)) {
            const float* adj = (t < 17) ? adj1 : adj2;
            float*       A   = (t < 17) ? A1f  : A2f;
            int row = (t < 17) ? t : (t - 32);
            float v[17]; float mx = -1e30f;
            for (int j = 0; j < 17; ++j) { v[j] = adj[row * 17 + j]; mx = fmaxf(mx, v[j]); }
            float s = 0.0f;
            for (int j = 0; j < 17; ++j) { v[j] = __expf(v[j] - mx); s += v[j]; }
            float inv = 1.0f / s;
            for (int j = 0; j < 17; ++j) A[row * 17 + j] = v[j] * inv;
        }
    }
}

// ---------------- main fused kernel ----------------
__global__ __launch_bounds__(256, 2)
void gat_main(const float* __restrict__ x,
              const float* __restrict__ b1, const float* __restrict__ b2,
              const float* __restrict__ bg1, const float* __restrict__ bg2,
              const bf16* __restrict__ w1t, const bf16* __restrict__ w2t,
              const bf16* __restrict__ wg1t, const bf16* __restrict__ wg2t,
              const float* __restrict__ A1, const float* __restrict__ A2,
              const float* __restrict__ Wc, const float* __restrict__ bc,
              float* __restrict__ out) {
    __shared__ alignas(16) bf16 S[S_ELEMS];
    bf16* xs = S;            // [32][SX]
    bf16* hs = S + 4352;     // [32][SH]
    bf16* ms = S + MS_BASE;  // [272][SMS]

    const int tid  = threadIdx.x;
    const int w    = tid >> 6;
    const int lane = tid & 63;
    const int l    = lane & 15;
    const int q    = lane >> 4;
    const int t0   = blockIdx.x * MT;

    // ---- stage x tile (fp32 -> bf16) ----
    for (int c = tid; c < 1024; c += 256) {
        int row = c >> 5, c4 = c & 31;
        const float4 v = *reinterpret_cast<const float4*>(x + (size_t)(t0 + row) * 128 + c4 * 4);
        bf16 tmp[4] = { __float2bfloat16(v.x), __float2bfloat16(v.y),
                        __float2bfloat16(v.z), __float2bfloat16(v.w) };
        *reinterpret_cast<ushort4*>(xs + row * SX + c4 * 4) =
            *reinterpret_cast<const ushort4*>(tmp);
    }
    __syncthreads();

    // ---- GEMM1: h = gelu(x @ W1 + b1)  [32,128]@[128,256] ----
    for (int nt = w * 4; nt < w * 4 + 4; ++nt) {
        int n = nt * 16 + l;
        bf16x8 bfr[4];
        const bf16* wp = w1t + n * 128 + q * 8;
#pragma unroll
        for (int kf = 0; kf < 4; ++kf) bfr[kf] = ld8(wp + kf * 32);
        float bias = b1[n];
#pragma unroll
        for (int mt = 0; mt < 2; ++mt) {
            f32x4 acc = {0.f, 0.f, 0.f, 0.f};
            const bf16* ap = xs + (mt * 16 + l) * SX + q * 8;
#pragma unroll
            for (int kf = 0; kf < 4; ++kf)
                acc = mfma16(ld8(ap + kf * 32), bfr[kf], acc);
            int trow = mt * 16 + q * 4;
#pragma unroll
            for (int r = 0; r < 4; ++r)
                hs[(trow + r) * SH + n] = __float2bfloat16(gelu_f(acc[r] + bias));
        }
    }
    __syncthreads();

    // ---- GEMM2: nodes = h @ W2 + b2 -> NTF[t][f][i] scatter (overlays xs+hs) ----
    {
        bf16x8 af[2][8];    // register-capture all of this thread's hs fragments
#pragma unroll
        for (int mt = 0; mt < 2; ++mt)
#pragma unroll
            for (int kf = 0; kf < 8; ++kf)
                af[mt][kf] = ld8(hs + (mt * 16 + l) * SH + kf * 32 + q * 8);
        __syncthreads();     // hs fully captured before NTF (overlaying) is written

        // zero NTF pad: j=17..19 of every (t,f) row + 16-elem tail (mix over-reads hit these)
        for (int z = tid; z < 3072; z += 256) {
            int row = z / 3, k = z - row * 3;
            S[row * SJ + 17 + k] = __float2bfloat16(0.f);
        }
        if (tid < 16) S[NTF_ELEMS + tid] = __float2bfloat16(0.f);

        for (int nt = w; nt < 34; nt += 4) {
            int n = nt * 16 + l;
            float bias = b2[n];
            int i = n >> 5, f = n & 31;
            f32x4 a0 = {0.f, 0.f, 0.f, 0.f}, a1 = {0.f, 0.f, 0.f, 0.f};
            const bf16* wp = w2t + n * 256 + q * 8;
#pragma unroll
            for (int kf = 0; kf < 8; ++kf) {
                bf16x8 bfr = ld8(wp + kf * 32);
                a0 = mfma16(af[0][kf], bfr, a0);
                a1 = mfma16(af[1][kf], bfr, a1);
            }
#pragma unroll
            for (int mt = 0; mt < 2; ++mt) {
                const f32x4 acc = mt ? a1 : a0;
#pragma unroll
                for (int r = 0; r < 4; ++r) {
                    int t = mt * 16 + q * 4 + r;
                    S[t * TFS + f * SJ + i] = __float2bfloat16(acc[r] + bias);
                }
            }
        }
    }
    __syncthreads();

    // ---- two GAT layers: mix (MFMA, adjacency in registers) + Wg GEMM, per 16-token half ----
    for (int g = 0; g < 2; ++g) {
        const float* A  = g ? A2 : A1;
        const bf16* wgt = g ? wg2t : wg1t;
        const float* bg = g ? bg2 : bg1;

        // mix B-frags: B[k=j][col=i] = A_soft[i][j]; exact zeros for i>=17 or j>=17
        bf16x8 mixB[2];
#pragma unroll
        for (int nt = 0; nt < 2; ++nt) {
            int i = nt * 16 + l;
            bf16 tmp[8];
#pragma unroll
            for (int e = 0; e < 8; ++e) {
                int j = q * 8 + e;
                float v = (i < 17 && j < 17) ? A[i * 17 + j] : 0.0f;
                tmp[e] = __float2bfloat16(v);
            }
            mixB[nt] = *reinterpret_cast<bf16x8*>(tmp);
        }
        bf16x8 wfr[2];
#pragma unroll
        for (int nt = 0; nt < 2; ++nt) wfr[nt] = ld8(wgt + (nt * 16 + l) * 32 + q * 8);
        float bgf[2] = { bg[l], bg[16 + l] };

        for (int half = 0; half < 2; ++half) {
            // ---- mix GEMM: mixT[(t,f)][i] = sum_j NTF[t][f][j] * A[i][j] -> Ms[(tloc,i)][f]
            for (int mt = w; mt < 32; mt += 4) {
                int R = half * 512 + mt * 16 + l;            // (t*32+f) row
                bf16x8 afr = ld8u(S + R * SJ + q * 8);       // pad/overread killed by mixB zeros
                int R0   = mt * 16 + q * 4;                  // this thread's D-row base
                int tloc = R0 >> 5, f0 = R0 & 31;            // 4 consecutive f, one token
#pragma unroll
                for (int nt = 0; nt < 2; ++nt) {
                    f32x4 acc = {0.f, 0.f, 0.f, 0.f};
                    acc = mfma16(afr, mixB[nt], acc);
                    int i = nt * 16 + l;
                    if (i < 17) {
                        int s = tloc * 17 + i;
                        union { ushort4 u; bf16 b[4]; } pk;
#pragma unroll
                        for (int r = 0; r < 4; ++r) pk.b[r] = __float2bfloat16(acc[r]);
                        *reinterpret_cast<ushort4*>(ms + s * SMS + f0) = pk.u;
                    }
                }
            }
            __syncthreads();

            // ---- Wg GEMM + gelu + residual, RMW into NTF (owner-exclusive cells) ----
            for (int mt = w; mt < 17; mt += 4) {
                bf16x8 afr = ld8(ms + (mt * 16 + l) * SMS + q * 8);
#pragma unroll
                for (int nt = 0; nt < 2; ++nt) {
                    f32x4 acc = {0.f, 0.f, 0.f, 0.f};
                    acc = mfma16(afr, wfr[nt], acc);
                    int fp = nt * 16 + l;
#pragma unroll
                    for (int r = 0; r < 4; ++r) {
                        int s    = mt * 16 + q * 4 + r;      // 0..271
                        int tloc = s / 17;
                        int i    = s - tloc * 17;
                        int off  = (half * 16 + tloc) * TFS + fp * SJ + i;
                        float v  = gelu_f(acc[r] + bgf[nt]) + bf2f(S[off]);
                        S[off]   = __float2bfloat16(v);
                    }
                }
            }
            __syncthreads();
        }
    }

    // ---- coord projection: out = g2 @ Wc + bc (fp32 output) ----
    for (int r = tid; r < 544; r += 256) {
        int t = r / 17, i = r % 17;
        float o0 = bc[0], o1 = bc[1];
        const bf16* gp = S + t * TFS + i;
#pragma unroll
        for (int f = 0; f < 32; ++f) {
            float v = bf2f(gp[f * SJ]);
            o0 = fmaf(v, Wc[f * 2 + 0], o0);
            o1 = fmaf(v, Wc[f * 2 + 1], o1);
        }
        float2 pr = { o0, o1 };
        reinterpret_cast<float2*>(out)[(size_t)(t0 + t) * 17 + i] = pr;
    }
}

extern "C" void kernel_launch(void* const* d_in, const int* in_sizes, int n_in,
                              void* d_out, int out_size, void* d_ws, size_t ws_size,
                              hipStream_t stream) {
    const float* x    = (const float*)d_in[0];
    const float* W1   = (const float*)d_in[1];
    const float* b1   = (const float*)d_in[2];
    const float* W2   = (const float*)d_in[3];
    const float* b2   = (const float*)d_in[4];
    const float* adj1 = (const float*)d_in[5];
    const float* Wg1  = (const float*)d_in[6];
    const float* bg1  = (const float*)d_in[7];
    const float* adj2 = (const float*)d_in[8];
    const float* Wg2  = (const float*)d_in[9];
    const float* bg2  = (const float*)d_in[10];
    const float* Wc   = (const float*)d_in[11];
    const float* bc   = (const float*)d_in[12];

    char* ws = (char*)d_ws;
    bf16*  w1t  = (bf16*)(ws + 0);        // 65536 B
    bf16*  w2t  = (bf16*)(ws + 65536);    // 278528 B
    bf16*  wg1t = (bf16*)(ws + 344064);   // 2048 B
    bf16*  wg2t = (bf16*)(ws + 346112);   // 2048 B
    float* A1f  = (float*)(ws + 348160);  // 1156 B
    float* A2f  = (float*)(ws + 349376);  // 1156 B

    prep_kernel<<<680, 256, 0, stream>>>(W1, W2, Wg1, Wg2, adj1, adj2,
                                         w1t, w2t, wg1t, wg2t, A1f, A2f);

    const int tokens = 16 * 4096;
    gat_main<<<tokens / MT, 256, 0, stream>>>(x, b1, b2, bg1, bg2,
                                              w1t, w2t, wg1t, wg2t,
                                              A1f, A2f, Wc, bc, (float*)d_out);
}

// Round 4
// 264.903 us; speedup vs baseline: 1.3430x; 1.0337x over previous
//
#include <hip/hip_runtime.h>
#include <hip/hip_bf16.h>

using bf16 = __hip_bfloat16;
typedef __bf16 bf16x4v __attribute__((ext_vector_type(4)));
typedef __bf16 bf16x8 __attribute__((ext_vector_type(8)));
typedef float f32x4 __attribute__((ext_vector_type(4)));

#define MT 32            // tokens per block
#define SX 136           // xs row stride: 128 + 8 pad
#define SH 264           // hs row stride: 256 + 8
#define SJ 20            // NTF j-stride: 17 joints + 3 zero pad (40 B rows)
#define TFS 640          // NTF token stride = 32 * SJ
#define NTF_ELEMS 20480  // 32 tokens * 32 feats * SJ
#define MS_BASE 20496    // NTF + 16-elem zeroed tail
#define SMS 36           // Ms row stride (72 B, 8B-aligned; 18*l mod 32 distinct -> conflict-free)
#define MSW 2880         // per-wave Ms region: [80][36]
#define S_ELEMS 32016    // 20496 + 4*2880 = 64032 B static LDS -> 2 blocks/CU
// LDS plan:
//   xs [32][136] @ 0, hs [32][264] @ 4352    (GEMM1 phase; dead after hs reg-capture)
//   NTF[t][f][j] @ 0  (t*640 + f*20 + j)     node state, overlays xs+hs
//   Ms  @ 20496 + w*2880: per-WAVE [80][36]  i-major scratch (row = i*4 + tok_in_chunk)
// After the GEMM2 barrier, ALL accesses are wave-local: no __syncthreads in GAT/coord.

__device__ __forceinline__ float bf2f(bf16 v) { return __bfloat162float(v); }

__device__ __forceinline__ float gelu_f(float x) {
    // tanh-approx GELU; |err vs erf-gelu| <= ~3e-3 abs, fine vs 2%-of-max threshold
    float u  = 0.7978845608f * x * (1.0f + 0.044715f * x * x);
    float au = fabsf(u);
    float e  = __expf(-2.0f * au);
    float t  = (1.0f - e) / (1.0f + e);
    t = (u < 0.0f) ? -t : t;
    return 0.5f * x * (1.0f + t);
}

__device__ __forceinline__ bf16x8 ld8(const bf16* p) {       // 16B-aligned
    return *reinterpret_cast<const bf16x8*>(p);
}
__device__ __forceinline__ bf16x8 ld8u(const bf16* p) {      // 8B-aligned (two b64)
    bf16x4v lo = *reinterpret_cast<const bf16x4v*>(p);
    bf16x4v hi = *reinterpret_cast<const bf16x4v*>(p + 4);
    return __builtin_shufflevector(lo, hi, 0, 1, 2, 3, 4, 5, 6, 7);
}
__device__ __forceinline__ f32x4 mfma16(bf16x8 a, bf16x8 b, f32x4 c) {
    return __builtin_amdgcn_mfma_f32_16x16x32_bf16(a, b, c, 0, 0, 0);
}

// ---------------- prep: weight transposes + adjacency softmax ----------------
__global__ void prep_kernel(const float* __restrict__ W1, const float* __restrict__ W2,
                            const float* __restrict__ Wg1, const float* __restrict__ Wg2,
                            const float* __restrict__ adj1, const float* __restrict__ adj2,
                            bf16* __restrict__ w1t, bf16* __restrict__ w2t,
                            bf16* __restrict__ wg1t, bf16* __restrict__ wg2t,
                            float* __restrict__ A1f, float* __restrict__ A2f) {
    int idx = blockIdx.x * 256 + threadIdx.x;
    if (idx < 32768) {                       // W1: r=k(128), c=n(256)
        int r = idx >> 8, c = idx & 255;
        w1t[c * 128 + r] = __float2bfloat16(W1[idx]);
    } else if (idx < 172032) {               // W2: r=k(256), c=n(544)
        int j = idx - 32768;
        int r = j / 544, c = j % 544;
        w2t[c * 256 + r] = __float2bfloat16(W2[j]);
    } else if (idx < 173056) {               // Wg1 -> wg1t[f'][f]
        int j = idx - 172032;
        wg1t[(j & 31) * 32 + (j >> 5)] = __float2bfloat16(Wg1[j]);
    } else if (idx < 174080) {
        int j = idx - 173056;
        wg2t[(j & 31) * 32 + (j >> 5)] = __float2bfloat16(Wg2[j]);
    }
    if (blockIdx.x == 0) {
        int t = threadIdx.x;
        if (t < 17 || (t >= 32 && t < 49)) {
            const float* adj = (t < 17) ? adj1 : adj2;
            float*       A   = (t < 17) ? A1f  : A2f;
            int row = (t < 17) ? t : (t - 32);
            float v[17]; float mx = -1e30f;
            for (int j = 0; j < 17; ++j) { v[j] = adj[row * 17 + j]; mx = fmaxf(mx, v[j]); }
            float s = 0.0f;
            for (int j = 0; j < 17; ++j) { v[j] = __expf(v[j] - mx); s += v[j]; }
            float inv = 1.0f / s;
            for (int j = 0; j < 17; ++j) A[row * 17 + j] = v[j] * inv;
        }
    }
}

// ---------------- main fused kernel ----------------
__global__ __launch_bounds__(256, 2)
void gat_main(const float* __restrict__ x,
              const float* __restrict__ b1, const float* __restrict__ b2,
              const float* __restrict__ bg1, const float* __restrict__ bg2,
              const bf16* __restrict__ w1t, const bf16* __restrict__ w2t,
              const bf16* __restrict__ wg1t, const bf16* __restrict__ wg2t,
              const float* __restrict__ A1, const float* __restrict__ A2,
              const float* __restrict__ Wc, const float* __restrict__ bc,
              float* __restrict__ out) {
    __shared__ alignas(16) bf16 S[S_ELEMS];
    bf16* xs = S;            // [32][SX]
    bf16* hs = S + 4352;     // [32][SH]

    const int tid  = threadIdx.x;
    const int w    = tid >> 6;
    const int lane = tid & 63;
    const int l    = lane & 15;
    const int q    = lane >> 4;
    const int t0   = blockIdx.x * MT;

    // ---- stage x tile (fp32 -> bf16) ----
    for (int c = tid; c < 1024; c += 256) {
        int row = c >> 5, c4 = c & 31;
        const float4 v = *reinterpret_cast<const float4*>(x + (size_t)(t0 + row) * 128 + c4 * 4);
        bf16 tmp[4] = { __float2bfloat16(v.x), __float2bfloat16(v.y),
                        __float2bfloat16(v.z), __float2bfloat16(v.w) };
        *reinterpret_cast<ushort4*>(xs + row * SX + c4 * 4) =
            *reinterpret_cast<const ushort4*>(tmp);
    }
    __syncthreads();

    // ---- GEMM1: h = gelu(x @ W1 + b1)  [32,128]@[128,256] ----
    for (int nt = w * 4; nt < w * 4 + 4; ++nt) {
        int n = nt * 16 + l;
        bf16x8 bfr[4];
        const bf16* wp = w1t + n * 128 + q * 8;
#pragma unroll
        for (int kf = 0; kf < 4; ++kf) bfr[kf] = ld8(wp + kf * 32);
        float bias = b1[n];
#pragma unroll
        for (int mt = 0; mt < 2; ++mt) {
            f32x4 acc = {0.f, 0.f, 0.f, 0.f};
            const bf16* ap = xs + (mt * 16 + l) * SX + q * 8;
#pragma unroll
            for (int kf = 0; kf < 4; ++kf)
                acc = mfma16(ld8(ap + kf * 32), bfr[kf], acc);
            int trow = mt * 16 + q * 4;
#pragma unroll
            for (int r = 0; r < 4; ++r)
                hs[(trow + r) * SH + n] = __float2bfloat16(gelu_f(acc[r] + bias));
        }
    }
    __syncthreads();

    // ---- GEMM2: nodes = h @ W2 + b2 -> NTF[t][f][i] scatter (overlays xs+hs) ----
    {
        bf16x8 af[2][8];    // register-capture all of this thread's hs fragments
#pragma unroll
        for (int mt = 0; mt < 2; ++mt)
#pragma unroll
            for (int kf = 0; kf < 8; ++kf)
                af[mt][kf] = ld8(hs + (mt * 16 + l) * SH + kf * 32 + q * 8);
        __syncthreads();     // hs fully captured before NTF (overlaying) is written

        // zero NTF pad: j=17..19 of every (t,f) row + 16-elem tail (mix over-reads
        // hit these; must be non-NaN; mixB zeros annihilate their contribution)
        for (int z = tid; z < 3072; z += 256) {
            int row = z / 3, k = z - row * 3;
            S[row * SJ + 17 + k] = __float2bfloat16(0.f);
        }
        if (tid < 16) S[NTF_ELEMS + tid] = __float2bfloat16(0.f);

        for (int nt = w; nt < 34; nt += 4) {
            int n = nt * 16 + l;
            float bias = b2[n];
            int i = n >> 5, f = n & 31;
            f32x4 a0 = {0.f, 0.f, 0.f, 0.f}, a1 = {0.f, 0.f, 0.f, 0.f};
            const bf16* wp = w2t + n * 256 + q * 8;
#pragma unroll
            for (int kf = 0; kf < 8; ++kf) {
                bf16x8 bfr = ld8(wp + kf * 32);
                a0 = mfma16(af[0][kf], bfr, a0);
                a1 = mfma16(af[1][kf], bfr, a1);
            }
#pragma unroll
            for (int mt = 0; mt < 2; ++mt) {
                const f32x4 acc = mt ? a1 : a0;
#pragma unroll
                for (int r = 0; r < 4; ++r) {
                    int t = mt * 16 + q * 4 + r;
                    S[t * TFS + f * SJ + i] = __float2bfloat16(acc[r] + bias);
                }
            }
        }
    }
    __syncthreads();
    // ======== from here on, everything is WAVE-LOCAL: no more barriers ========

    bf16* ms_w = S + MS_BASE + w * MSW;    // this wave's [80][36] scratch

    for (int g = 0; g < 2; ++g) {
        const float* A  = g ? A2 : A1;
        const bf16* wgt = g ? wg2t : wg1t;
        const float* bg = g ? bg2 : bg1;

        // mix B-frags: B[k=j][col=i] = A_soft[i][j]; exact zeros for i>=17 or j>=17
        bf16x8 mixB[2];
#pragma unroll
        for (int nt = 0; nt < 2; ++nt) {
            int i = nt * 16 + l;
            bf16 tmp[8];
#pragma unroll
            for (int e = 0; e < 8; ++e) {
                int j = q * 8 + e;
                float v = (i < 17 && j < 17) ? A[i * 17 + j] : 0.0f;
                tmp[e] = __float2bfloat16(v);
            }
            mixB[nt] = *reinterpret_cast<bf16x8*>(tmp);
        }
        bf16x8 wfr[2];
#pragma unroll
        for (int nt = 0; nt < 2; ++nt) wfr[nt] = ld8(wgt + (nt * 16 + l) * 32 + q * 8);
        float bgf[2] = { bg[l], bg[16 + l] };

        // two 4-token chunks per wave
        for (int c = 0; c < 2; ++c) {
            // ---- mix GEMM: mixT[(t,f)][i] -> ms_w[(i*4 + tl)][f]  (i-major) ----
#pragma unroll
            for (int mt2 = c * 8; mt2 < c * 8 + 8; ++mt2) {
                int R = w * 256 + mt2 * 16 + l;          // (t*32+f) row of NTF
                bf16x8 afr = ld8u(S + R * SJ + q * 8);   // pad/overread killed by mixB zeros
                int rr0 = mt2 * 16 + q * 4;              // D-row base (within wave)
                int f0  = rr0 & 31;                      // 4 consecutive f
                int tl  = (rr0 >> 5) & 3;                // token in chunk (uniform per mt2,q)
#pragma unroll
                for (int nt = 0; nt < 2; ++nt) {
                    f32x4 acc = {0.f, 0.f, 0.f, 0.f};
                    acc = mfma16(afr, mixB[nt], acc);
                    int i = nt * 16 + l;
                    if (i < 17) {
                        union { ushort4 u; bf16 b[4]; } pk;
#pragma unroll
                        for (int r = 0; r < 4; ++r) pk.b[r] = __float2bfloat16(acc[r]);
                        *reinterpret_cast<ushort4*>(ms_w + (i * 4 + tl) * SMS + f0) = pk.u;
                    }
                }
            }

            // ---- Wg GEMM + gelu + residual RMW into NTF (owner-exclusive cells) ----
            // Ms rows: s' = i*4 + tl; tile mt -> i = 4*mt + q (uniform), tl = r. No div17.
#pragma unroll
            for (int mt = 0; mt < 5; ++mt) {
                bf16x8 afr = ld8u(ms_w + (mt * 16 + l) * SMS + q * 8);
                int i = mt * 4 + q;
                bool iv = (i < 17);                      // tile 4: only q=0 valid
#pragma unroll
                for (int nt = 0; nt < 2; ++nt) {
                    f32x4 acc = {0.f, 0.f, 0.f, 0.f};
                    acc = mfma16(afr, wfr[nt], acc);
                    int fp = nt * 16 + l;
                    if (iv) {
                        int base = (w * 8 + c * 4) * TFS + fp * SJ + i;
#pragma unroll
                        for (int r = 0; r < 4; ++r) {
                            int off = base + r * TFS;    // token = chunk-base + r
                            float v = gelu_f(acc[r] + bgf[nt]) + bf2f(S[off]);
                            S[off]  = __float2bfloat16(v);
                        }
                    }
                }
            }
        }
    }

    // ---- coord projection (wave-local): out = g2 @ Wc + bc (fp32 output) ----
    for (int s = lane; s < 136; s += 64) {
        int tl = s / 17, i = s - tl * 17;
        int t  = w * 8 + tl;
        const bf16* gp = S + t * TFS + i;
        float o0 = bc[0], o1 = bc[1];
#pragma unroll
        for (int f = 0; f < 32; ++f) {
            float v = bf2f(gp[f * SJ]);
            o0 = fmaf(v, Wc[f * 2 + 0], o0);
            o1 = fmaf(v, Wc[f * 2 + 1], o1);
        }
        float2 pr = { o0, o1 };
        reinterpret_cast<float2*>(out)[(size_t)(t0 + t) * 17 + i] = pr;
    }
}

extern "C" void kernel_launch(void* const* d_in, const int* in_sizes, int n_in,
                              void* d_out, int out_size, void* d_ws, size_t ws_size,
                              hipStream_t stream) {
    const float* x    = (const float*)d_in[0];
    const float* W1   = (const float*)d_in[1];
    const float* b1   = (const float*)d_in[2];
    const float* W2   = (const float*)d_in[3];
    const float* b2   = (const float*)d_in[4];
    const float* adj1 = (const float*)d_in[5];
    const float* Wg1  = (const float*)d_in[6];
    const float* bg1  = (const float*)d_in[7];
    const float* adj2 = (const float*)d_in[8];
    const float* Wg2  = (const float*)d_in[9];
    const float* bg2  = (const float*)d_in[10];
    const float* Wc   = (const float*)d_in[11];
    const float* bc   = (const float*)d_in[12];

    char* ws = (char*)d_ws;
    bf16*  w1t  = (bf16*)(ws + 0);        // 65536 B
    bf16*  w2t  = (bf16*)(ws + 65536);    // 278528 B
    bf16*  wg1t = (bf16*)(ws + 344064);   // 2048 B
    bf16*  wg2t = (bf16*)(ws + 346112);   // 2048 B
    float* A1f  = (float*)(ws + 348160);  // 1156 B
    float* A2f  = (float*)(ws + 349376);  // 1156 B

    prep_kernel<<<680, 256, 0, stream>>>(W1, W2, Wg1, Wg2, adj1, adj2,
                                         w1t, w2t, wg1t, wg2t, A1f, A2f);

    const int tokens = 16 * 4096;
    gat_main<<<tokens / MT, 256, 0, stream>>>(x, b1, b2, bg1, bg2,
                                              w1t, w2t, wg1t, wg2t,
                                              A1f, A2f, Wc, bc, (float*)d_out);
}

// Round 5
// 249.773 us; speedup vs baseline: 1.4244x; 1.0606x over previous
//
#include <hip/hip_runtime.h>
#include <hip/hip_bf16.h>

using bf16 = __hip_bfloat16;
typedef __bf16 bf16x4v __attribute__((ext_vector_type(4)));
typedef __bf16 bf16x8 __attribute__((ext_vector_type(8)));
typedef float f32x4 __attribute__((ext_vector_type(4)));

#define MT 32            // tokens per block
#define SX 136           // xs row stride: 128 + 8 pad
#define SH 264           // hs row stride: 256 + 8
#define SJ 20            // NTF j-stride: 17 joints + 3 zero pad (40 B rows)
#define TFS 640          // NTF token stride = 32 * SJ
#define NTF_ELEMS 20480  // 32 tokens * 32 feats * SJ
#define MS_BASE 20496    // NTF + 16-elem zeroed tail
#define SMS 36           // Ms row stride (72 B, 8B-aligned)
#define MSW 1440         // per-wave Ms region: [40][36] (2-token chunks)
#define S_ELEMS 32304    // 20496 + 8*1440 + 288 overread tail = 64608 B -> 2 blocks/CU
// 512 threads (8 waves), 2 blocks/CU => 16 waves/CU = 4 waves/SIMD (vs 2 before).
// LDS plan:
//   xs [32][136] @ 0, hs [32][264] @ 4352    (GEMM1 phase; dead after hs reg-capture)
//   NTF[t][f][j] @ 0  (t*640 + f*20 + j)     node state, overlays xs+hs
//   Ms  @ 20496 + w*1440: per-WAVE [40][36]  i-major scratch (row = i*2 + tok_in_chunk)
// After the GEMM2 barrier, ALL accesses are wave-local: no __syncthreads in GAT/coord.
// Wg m-tile 2 reads Ms rows 32..47: rows >=40 land in the next wave's region or the
// 288-elem tail (wave 7) -- garbage is safe: MFMA rows are row-confined and every
// D-row with i>=17 is store-guarded.

__device__ __forceinline__ float bf2f(bf16 v) { return __bfloat162float(v); }

__device__ __forceinline__ float gelu_f(float x) {
    // tanh-approx GELU; |err vs erf-gelu| <= ~3e-3 abs, fine vs 2%-of-max threshold
    float u  = 0.7978845608f * x * (1.0f + 0.044715f * x * x);
    float au = fabsf(u);
    float e  = __expf(-2.0f * au);
    float t  = (1.0f - e) / (1.0f + e);
    t = (u < 0.0f) ? -t : t;
    return 0.5f * x * (1.0f + t);
}

__device__ __forceinline__ bf16x8 ld8(const bf16* p) {       // 16B-aligned
    return *reinterpret_cast<const bf16x8*>(p);
}
__device__ __forceinline__ bf16x8 ld8u(const bf16* p) {      // 8B-aligned (two b64)
    bf16x4v lo = *reinterpret_cast<const bf16x4v*>(p);
    bf16x4v hi = *reinterpret_cast<const bf16x4v*>(p + 4);
    return __builtin_shufflevector(lo, hi, 0, 1, 2, 3, 4, 5, 6, 7);
}
__device__ __forceinline__ f32x4 mfma16(bf16x8 a, bf16x8 b, f32x4 c) {
    return __builtin_amdgcn_mfma_f32_16x16x32_bf16(a, b, c, 0, 0, 0);
}

// ---------------- prep: weight transposes + adjacency softmax ----------------
__global__ void prep_kernel(const float* __restrict__ W1, const float* __restrict__ W2,
                            const float* __restrict__ Wg1, const float* __restrict__ Wg2,
                            const float* __restrict__ adj1, const float* __restrict__ adj2,
                            bf16* __restrict__ w1t, bf16* __restrict__ w2t,
                            bf16* __restrict__ wg1t, bf16* __restrict__ wg2t,
                            float* __restrict__ A1f, float* __restrict__ A2f) {
    int idx = blockIdx.x * 256 + threadIdx.x;
    if (idx < 32768) {                       // W1: r=k(128), c=n(256)
        int r = idx >> 8, c = idx & 255;
        w1t[c * 128 + r] = __float2bfloat16(W1[idx]);
    } else if (idx < 172032) {               // W2: r=k(256), c=n(544)
        int j = idx - 32768;
        int r = j / 544, c = j % 544;
        w2t[c * 256 + r] = __float2bfloat16(W2[j]);
    } else if (idx < 173056) {               // Wg1 -> wg1t[f'][f]
        int j = idx - 172032;
        wg1t[(j & 31) * 32 + (j >> 5)] = __float2bfloat16(Wg1[j]);
    } else if (idx < 174080) {
        int j = idx - 173056;
        wg2t[(j & 31) * 32 + (j >> 5)] = __float2bfloat16(Wg2[j]);
    }
    if (blockIdx.x == 0) {
        int t = threadIdx.x;
        if (t < 17 || (t >= 32 && t < 49)) {
            const float* adj = (t < 17) ? adj1 : adj2;
            float*       A   = (t < 17) ? A1f  : A2f;
            int row = (t < 17) ? t : (t - 32);
            float v[17]; float mx = -1e30f;
            for (int j = 0; j < 17; ++j) { v[j] = adj[row * 17 + j]; mx = fmaxf(mx, v[j]); }
            float s = 0.0f;
            for (int j = 0; j < 17; ++j) { v[j] = __expf(v[j] - mx); s += v[j]; }
            float inv = 1.0f / s;
            for (int j = 0; j < 17; ++j) A[row * 17 + j] = v[j] * inv;
        }
    }
}

// ---------------- main fused kernel ----------------
__global__ __launch_bounds__(512, 4)
void gat_main(const float* __restrict__ x,
              const float* __restrict__ b1, const float* __restrict__ b2,
              const float* __restrict__ bg1, const float* __restrict__ bg2,
              const bf16* __restrict__ w1t, const bf16* __restrict__ w2t,
              const bf16* __restrict__ wg1t, const bf16* __restrict__ wg2t,
              const float* __restrict__ A1, const float* __restrict__ A2,
              const float* __restrict__ Wc, const float* __restrict__ bc,
              float* __restrict__ out) {
    __shared__ alignas(16) bf16 S[S_ELEMS];
    bf16* xs = S;            // [32][SX]
    bf16* hs = S + 4352;     // [32][SH]

    const int tid  = threadIdx.x;
    const int w    = tid >> 6;      // 0..7
    const int lane = tid & 63;
    const int l    = lane & 15;
    const int q    = lane >> 4;
    const int t0   = blockIdx.x * MT;

    // ---- stage x tile (fp32 -> bf16) ----
    for (int c = tid; c < 1024; c += 512) {
        int row = c >> 5, c4 = c & 31;
        const float4 v = *reinterpret_cast<const float4*>(x + (size_t)(t0 + row) * 128 + c4 * 4);
        bf16 tmp[4] = { __float2bfloat16(v.x), __float2bfloat16(v.y),
                        __float2bfloat16(v.z), __float2bfloat16(v.w) };
        *reinterpret_cast<ushort4*>(xs + row * SX + c4 * 4) =
            *reinterpret_cast<const ushort4*>(tmp);
    }
    __syncthreads();

    // ---- GEMM1: h = gelu(x @ W1 + b1)  [32,128]@[128,256], 2 n-tiles/wave ----
    for (int nt = w * 2; nt < w * 2 + 2; ++nt) {
        int n = nt * 16 + l;
        bf16x8 bfr[4];
        const bf16* wp = w1t + n * 128 + q * 8;
#pragma unroll
        for (int kf = 0; kf < 4; ++kf) bfr[kf] = ld8(wp + kf * 32);
        float bias = b1[n];
#pragma unroll
        for (int mt = 0; mt < 2; ++mt) {
            f32x4 acc = {0.f, 0.f, 0.f, 0.f};
            const bf16* ap = xs + (mt * 16 + l) * SX + q * 8;
#pragma unroll
            for (int kf = 0; kf < 4; ++kf)
                acc = mfma16(ld8(ap + kf * 32), bfr[kf], acc);
            int trow = mt * 16 + q * 4;
#pragma unroll
            for (int r = 0; r < 4; ++r)
                hs[(trow + r) * SH + n] = __float2bfloat16(gelu_f(acc[r] + bias));
        }
    }
    __syncthreads();

    // ---- GEMM2: nodes = h @ W2 + b2 -> NTF[t][f][i] scatter (overlays xs+hs) ----
    {
        bf16x8 af[2][8];    // register-capture all of this thread's hs fragments
#pragma unroll
        for (int mt = 0; mt < 2; ++mt)
#pragma unroll
            for (int kf = 0; kf < 8; ++kf)
                af[mt][kf] = ld8(hs + (mt * 16 + l) * SH + kf * 32 + q * 8);
        __syncthreads();     // hs fully captured before NTF (overlaying) is written

        // zero NTF pad: j=17..19 of every (t,f) row + 16-elem tail (mix over-reads
        // hit these; must be non-NaN; mixB zeros annihilate their contribution)
        for (int z = tid; z < 3072; z += 512) {
            int row = z / 3, k = z - row * 3;
            S[row * SJ + 17 + k] = __float2bfloat16(0.f);
        }
        if (tid < 16) S[NTF_ELEMS + tid] = __float2bfloat16(0.f);

        for (int nt = w; nt < 34; nt += 8) {
            int n = nt * 16 + l;
            float bias = b2[n];
            int i = n >> 5, f = n & 31;
            f32x4 a0 = {0.f, 0.f, 0.f, 0.f}, a1 = {0.f, 0.f, 0.f, 0.f};
            const bf16* wp = w2t + n * 256 + q * 8;
#pragma unroll
            for (int kf = 0; kf < 8; ++kf) {
                bf16x8 bfr = ld8(wp + kf * 32);
                a0 = mfma16(af[0][kf], bfr, a0);
                a1 = mfma16(af[1][kf], bfr, a1);
            }
#pragma unroll
            for (int mt = 0; mt < 2; ++mt) {
                const f32x4 acc = mt ? a1 : a0;
#pragma unroll
                for (int r = 0; r < 4; ++r) {
                    int t = mt * 16 + q * 4 + r;
                    S[t * TFS + f * SJ + i] = __float2bfloat16(acc[r] + bias);
                }
            }
        }
    }
    __syncthreads();
    // ======== from here on, everything is WAVE-LOCAL: no more barriers ========

    bf16* ms_w = S + MS_BASE + w * MSW;    // this wave's [40][36] scratch

    for (int g = 0; g < 2; ++g) {
        const float* A  = g ? A2 : A1;
        const bf16* wgt = g ? wg2t : wg1t;
        const float* bg = g ? bg2 : bg1;

        // mix B-frags: B[k=j][col=i] = A_soft[i][j]; exact zeros for i>=17 or j>=17
        bf16x8 mixB[2];
#pragma unroll
        for (int nt = 0; nt < 2; ++nt) {
            int i = nt * 16 + l;
            bf16 tmp[8];
#pragma unroll
            for (int e = 0; e < 8; ++e) {
                int j = q * 8 + e;
                float v = (i < 17 && j < 17) ? A[i * 17 + j] : 0.0f;
                tmp[e] = __float2bfloat16(v);
            }
            mixB[nt] = *reinterpret_cast<bf16x8*>(tmp);
        }
        bf16x8 wfr[2];
#pragma unroll
        for (int nt = 0; nt < 2; ++nt) wfr[nt] = ld8(wgt + (nt * 16 + l) * 32 + q * 8);
        float bgf[2] = { bg[l], bg[16 + l] };

        // two 2-token chunks per wave (wave owns tokens w*4 .. w*4+3)
        for (int c = 0; c < 2; ++c) {
            // ---- mix GEMM: mixT[(t,f)][i] -> ms_w[(i*2 + tl)][f]  (i-major) ----
#pragma unroll
            for (int mt2 = 0; mt2 < 4; ++mt2) {
                int R = w * 128 + c * 64 + mt2 * 16 + l;   // NTF row (t*32+f)
                bf16x8 afr = ld8u(S + R * SJ + q * 8);     // pad/overread killed by mixB zeros
                int rr0 = mt2 * 16 + q * 4;                // D-row base within chunk
                int f0  = rr0 & 31;                        // 4 consecutive f
                int tl  = rr0 >> 5;                        // token in chunk (0..1)
#pragma unroll
                for (int nt = 0; nt < 2; ++nt) {
                    f32x4 acc = {0.f, 0.f, 0.f, 0.f};
                    acc = mfma16(afr, mixB[nt], acc);
                    int i = nt * 16 + l;
                    if (i < 17) {
                        union { ushort4 u; bf16 b[4]; } pk;
#pragma unroll
                        for (int r = 0; r < 4; ++r) pk.b[r] = __float2bfloat16(acc[r]);
                        *reinterpret_cast<ushort4*>(ms_w + (i * 2 + tl) * SMS + f0) = pk.u;
                    }
                }
            }

            // ---- Wg GEMM + gelu + residual RMW into NTF (owner-exclusive cells) ----
            // Ms rows: s' = i*2 + tl -> i = rr>>1, tl = rr&1. No div17 anywhere.
#pragma unroll
            for (int mt = 0; mt < 3; ++mt) {
                bf16x8 afr = ld8u(ms_w + (mt * 16 + l) * SMS + q * 8);
#pragma unroll
                for (int nt = 0; nt < 2; ++nt) {
                    f32x4 acc = {0.f, 0.f, 0.f, 0.f};
                    acc = mfma16(afr, wfr[nt], acc);
                    int fp = nt * 16 + l;
#pragma unroll
                    for (int r = 0; r < 4; ++r) {
                        int rr = mt * 16 + q * 4 + r;      // 0..47, valid < 34
                        int i  = rr >> 1;
                        int tl = rr & 1;
                        if (i < 17) {
                            int off = (w * 4 + c * 2 + tl) * TFS + fp * SJ + i;
                            float v = gelu_f(acc[r] + bgf[nt]) + bf2f(S[off]);
                            S[off]  = __float2bfloat16(v);
                        }
                    }
                }
            }
        }
    }

    // ---- coord projection (wave-local, 4 tokens): out = g2 @ Wc + bc ----
    for (int s = lane; s < 68; s += 64) {
        int tl = s / 17, i = s - tl * 17;
        int t  = w * 4 + tl;
        const bf16* gp = S + t * TFS + i;
        float o0 = bc[0], o1 = bc[1];
#pragma unroll
        for (int f = 0; f < 32; ++f) {
            float v = bf2f(gp[f * SJ]);
            o0 = fmaf(v, Wc[f * 2 + 0], o0);
            o1 = fmaf(v, Wc[f * 2 + 1], o1);
        }
        float2 pr = { o0, o1 };
        reinterpret_cast<float2*>(out)[(size_t)(t0 + t) * 17 + i] = pr;
    }
}

extern "C" void kernel_launch(void* const* d_in, const int* in_sizes, int n_in,
                              void* d_out, int out_size, void* d_ws, size_t ws_size,
                              hipStream_t stream) {
    const float* x    = (const float*)d_in[0];
    const float* W1   = (const float*)d_in[1];
    const float* b1   = (const float*)d_in[2];
    const float* W2   = (const float*)d_in[3];
    const float* b2   = (const float*)d_in[4];
    const float* adj1 = (const float*)d_in[5];
    const float* Wg1  = (const float*)d_in[6];
    const float* bg1  = (const float*)d_in[7];
    const float* adj2 = (const float*)d_in[8];
    const float* Wg2  = (const float*)d_in[9];
    const float* bg2  = (const float*)d_in[10];
    const float* Wc   = (const float*)d_in[11];
    const float* bc   = (const float*)d_in[12];

    char* ws = (char*)d_ws;
    bf16*  w1t  = (bf16*)(ws + 0);        // 65536 B
    bf16*  w2t  = (bf16*)(ws + 65536);    // 278528 B
    bf16*  wg1t = (bf16*)(ws + 344064);   // 2048 B
    bf16*  wg2t = (bf16*)(ws + 346112);   // 2048 B
    float* A1f  = (float*)(ws + 348160);  // 1156 B
    float* A2f  = (float*)(ws + 349376);  // 1156 B

    prep_kernel<<<680, 256, 0, stream>>>(W1, W2, Wg1, Wg2, adj1, adj2,
                                         w1t, w2t, wg1t, wg2t, A1f, A2f);

    const int tokens = 16 * 4096;
    gat_main<<<tokens / MT, 512, 0, stream>>>(x, b1, b2, bg1, bg2,
                                              w1t, w2t, wg1t, wg2t,
                                              A1f, A2f, Wc, bc, (float*)d_out);
}